// Round 10
// baseline (303.649 us; speedup 1.0000x reference)
//
#include <hip/hip_runtime.h>
#include <hip/hip_bf16.h>
#include <math.h>

typedef __hip_bfloat16 bf16;
typedef __attribute__((ext_vector_type(8))) short short8;
typedef __attribute__((ext_vector_type(4))) float f32x4;

#define NB 2
#define HH 96
#define WW 96
#define CC 256
#define NHEADS 8
#define PP 25
#define DHH 32
#define HIDN 1024
#define LQ (HH*WW)          // 9216
#define TT (NB*LQ)          // 18432
#define NVC 896             // 256 val + 400 off + 200 attn + 40 pad
#define TB 4                // tokens per sample block (1 per wave)
#define GW 6                // dedup grid width (cells)

__device__ __forceinline__ float b2f(bf16 v){ return __bfloat162float(v); }
__device__ __forceinline__ bf16  f2b(float v){ return __float2bfloat16(v); }
__device__ __forceinline__ float lo_bf(unsigned u){ return __uint_as_float(u << 16); }
__device__ __forceinline__ float hi_bf(unsigned u){ return __uint_as_float(u & 0xffff0000u); }

__device__ __forceinline__ void gl2lds16(const void* g, void* l) {
    __builtin_amdgcn_global_load_lds(
        (const __attribute__((address_space(1))) unsigned int*)g,
        (__attribute__((address_space(3))) unsigned int*)l, 16, 0, 0);
}

// ---------------- all weight prep in one kernel ---------------------------------
__global__ __launch_bounds__(256) void prep_all(const float* __restrict__ w_val,
                                                const float* __restrict__ w_off,
                                                const float* __restrict__ w_attn,
                                                const float* __restrict__ w_fc1,
                                                const float* __restrict__ w_fc2,
                                                const float* __restrict__ w_out,
                                                const float* __restrict__ b_val,
                                                const float* __restrict__ b_off,
                                                const float* __restrict__ b_attn,
                                                bf16* __restrict__ wvcT,
                                                bf16* __restrict__ wfc1T,
                                                bf16* __restrict__ wfc2T,
                                                bf16* __restrict__ woutT,
                                                float* __restrict__ bvc)
{
    const int idx = blockIdx.x*256 + threadIdx.x;   // < 819200
    if (idx < 229376) {                              // wvcT [896][256]
        int n = idx >> 8, k = idx & 255;
        float v = (n < 256) ? w_val[(size_t)k*256 + n]
                : (n < 656) ? w_off[(size_t)k*400 + (n-256)]
                : (n < 856) ? w_attn[(size_t)k*200 + (n-656)] : 0.f;
        wvcT[idx] = f2b(v);
    } else if (idx < 491520) {                       // wfc1T [1024][256]
        int j = idx - 229376; int n = j >> 8, k = j & 255;
        wfc1T[j] = f2b(w_fc1[(size_t)k*1024 + n]);
    } else if (idx < 753664) {                       // wfc2T [256][1024]
        int j = idx - 491520; int n = j >> 10, k = j & 1023;
        wfc2T[j] = f2b(w_fc2[(size_t)k*256 + n]);
    } else if (idx < 819200) {                       // woutT [256][256]
        int j = idx - 753664; int n = j >> 8, k = j & 255;
        woutT[j] = f2b(w_out[(size_t)k*256 + n]);
    }
    if (idx < NVC)
        bvc[idx] = (idx < 256) ? b_val[idx]
                 : (idx < 656) ? b_off[idx-256]
                 : (idx < 856) ? b_attn[idx-656] : 0.f;
}

// ---------------- LayerNorm: one wave per token, 4 ch/lane ----------------------
__global__ __launch_bounds__(256) void ln_kernel(const float* __restrict__ x,
                                                 const float* __restrict__ g,
                                                 const float* __restrict__ b,
                                                 bf16* __restrict__ out)
{
    const int t = blockIdx.x*4 + (threadIdx.x >> 6);
    const int l = threadIdx.x & 63;
    const float4 v = *(const float4*)(x + (size_t)t*CC + l*4);
    float s  = v.x + v.y + v.z + v.w;
    float s2 = v.x*v.x + v.y*v.y + v.z*v.z + v.w*v.w;
    #pragma unroll
    for (int m = 1; m < 64; m <<= 1) { s += __shfl_xor(s, m); s2 += __shfl_xor(s2, m); }
    const float mean = s * (1.f/CC);
    const float var  = s2 * (1.f/CC) - mean*mean;
    const float rs   = 1.f / sqrtf(var + 1e-5f);
    const float4 gg = *(const float4*)(g + l*4);
    const float4 bb = *(const float4*)(b + l*4);
    bf16 o[4];
    o[0] = f2b((v.x-mean)*rs*gg.x + bb.x);
    o[1] = f2b((v.y-mean)*rs*gg.y + bb.y);
    o[2] = f2b((v.z-mean)*rs*gg.z + bb.z);
    o[3] = f2b((v.w-mean)*rs*gg.w + bb.w);
    *(uint2*)(out + (size_t)t*CC + l*4) = *(uint2*)o;
}

// ---------------- MFMA GEMM: A[M,K]bf16 @ Bt[N,K]bf16 + bias fp32 --------------
// tile TMx128, BK=64, 4 waves; XOR-swizzled LDS chunks. Compile-time K,N,TM.
// EPI: 0 = bf16; 2 = gelu->bf16; 3 = +resid(fp32)->fp32;
//      4 = col<256 -> dense bf16 val_d[row][col] (row stride 256), else bf16 vc
template<int EPI, int K, int N, int TM>
__global__ __launch_bounds__(256) void mfma_gemm(const bf16* __restrict__ A,
                                                 const bf16* __restrict__ Bt,
                                                 const float* __restrict__ bias,
                                                 void* __restrict__ outv,
                                                 const float* __restrict__ resid,
                                                 bf16* __restrict__ val_d)
{
    constexpr int AR  = TM/8;        // A regions (8 rows each)
    constexpr int TR  = AR + 16;     // + B regions (128 rows)
    constexpr int RPW = TR/4;        // regions staged per wave
    constexpr int NJ  = (TM==128) ? 4 : 2;
    __shared__ short As[TM*64];
    __shared__ short Bs[128*64];
    const int tid = threadIdx.x;
    const int w = tid >> 6, l = tid & 63;
    const int bm = blockIdx.x, bn = blockIdx.y;

    const bf16* sbase[RPW];
    short*      lbase[RPW];
    {
        const int lrow = l >> 3;
        const int q    = (l & 7) ^ lrow;
        #pragma unroll
        for (int j = 0; j < RPW; j++) {
            int r = w*RPW + j;
            bool isA = r < AR;
            int rr = isA ? r : r - AR;
            int row = rr*8 + lrow;
            size_t grow = (size_t)(isA ? (bm*TM + row) : (bn*128 + row));
            sbase[j] = (isA ? A : Bt) + grow*K + q*8;
            lbase[j] = (isA ? As : Bs) + rr*512;
        }
    }

    const int mbase = (TM==128) ? 64*(w >> 1) : 0;
    const int nbase = (TM==128) ? 64*(w & 1)  : 32*w;

    int aoff[2][4], boff[2][NJ];
    #pragma unroll
    for (int s = 0; s < 2; s++) {
        const int q = s*4 + (l >> 4);
        #pragma unroll
        for (int i = 0; i < 4; i++) {
            int m = mbase + i*16 + (l & 15);
            aoff[s][i] = (m*8 + (q ^ (m & 7))) * 8;
        }
        #pragma unroll
        for (int j = 0; j < NJ; j++) {
            int n = nbase + j*16 + (l & 15);
            boff[s][j] = (n*8 + (q ^ (n & 7))) * 8;
        }
    }

    f32x4 acc[4][NJ];
    #pragma unroll
    for (int i = 0; i < 4; i++)
        #pragma unroll
        for (int j = 0; j < NJ; j++)
            acc[i][j] = (f32x4){0.f, 0.f, 0.f, 0.f};

    for (int k0 = 0; k0 < K; k0 += 64) {
        #pragma unroll
        for (int j = 0; j < RPW; j++)
            gl2lds16(sbase[j] + k0, lbase[j]);
        __syncthreads();
        #pragma unroll
        for (int s = 0; s < 2; s++) {
            short8 af[4], bfr[NJ];
            #pragma unroll
            for (int i = 0; i < 4; i++)  af[i]  = *(const short8*)(As + aoff[s][i]);
            #pragma unroll
            for (int j = 0; j < NJ; j++) bfr[j] = *(const short8*)(Bs + boff[s][j]);
            #pragma unroll
            for (int i = 0; i < 4; i++)
                #pragma unroll
                for (int j = 0; j < NJ; j++)
                    acc[i][j] = __builtin_amdgcn_mfma_f32_16x16x32_bf16(af[i], bfr[j], acc[i][j], 0, 0, 0);
        }
        __syncthreads();
    }

    const int row0 = bm*TM + mbase + (l >> 4)*4;
    const int col0 = bn*128 + nbase + (l & 15);
    #pragma unroll
    for (int i = 0; i < 4; i++) {
        #pragma unroll
        for (int j = 0; j < NJ; j++) {
            const int col = col0 + j*16;
            const float bs = bias[col];
            #pragma unroll
            for (int r = 0; r < 4; r++) {
                const int row = row0 + i*16 + r;
                float v = acc[i][j][r] + bs;
                size_t o = (size_t)row * N + col;
                if (EPI == 0) {
                    ((bf16*)outv)[o] = f2b(v);
                } else if (EPI == 2) {
                    ((bf16*)outv)[o] = f2b(0.5f * v * (1.f + erff(v * 0.70710678118654752f)));
                } else if (EPI == 3) {
                    ((float*)outv)[o] = v + resid[o];
                } else { // 4: val cols -> dense [row][256] buffer; rest -> vc
                    if (col < 256) val_d[(size_t)row*CC + col] = f2b(v);
                    else           ((bf16*)outv)[o] = f2b(v);
                }
            }
        }
    }
}

// ---------------- Deformable sampling with tap dedup ----------------------------
// block = 4 tokens, 256 threads, one token per wave.
// Phase 1: 32 (t,h) pairs x 8 threads: softmax (xor 1,2,4) + point coords;
//   shuffle min/max bounding box of clamped tap pixels. If box <= 6x6 (typical:
//   offsets are tiny so all 25 pts cluster), scatter fp32 tap weights into a
//   36-cell LDS grid (ds_add_f32) -> exact regrouping of the bilinear sum.
//   Else fallback: store 16B Tap records (R9 path).
// Phase 2: lane = (head, 4-ch group): iterate grid cells, gather each unique
//   pixel ONCE (8B/lane), FMA with accumulated cell weight.
struct __align__(16) Tap { _Float16 w[4]; unsigned short i[4]; };

__global__ __launch_bounds__(256) void sample_kernel(const bf16* __restrict__ vc,
                                                     const bf16* __restrict__ val_d,
                                                     const float* __restrict__ refp,
                                                     bf16* __restrict__ samp)
{
    __shared__ Tap   taps[TB*200];          // 12800 B (fallback only)
    __shared__ float sgrid[TB*8*36];        //  4608 B
    __shared__ int   smeta[TB*8];           //   128 B
    const int b = blockIdx.x;                        // 4608 blocks
    const int xcd = b & 7, sub = b >> 3;             // 576 subs per xcd
    const int tbase = (xcd >> 2)*LQ + ((xcd & 3)*576 + sub)*TB;
    const int tid = threadIdx.x;

    // zero dedup grid
    #pragma unroll
    for (int i = tid; i < TB*8*36; i += 256) sgrid[i] = 0.f;

    // ---- phase 1: 8 threads per (t,h) pair
    {
        const int pair = tid >> 3;                   // 0..31 = (tl, h)
        const int j    = tid & 7;                    // point sub-lane
        const int tl   = pair >> 3;
        const int h    = pair & 7;
        const int t    = tbase + tl;
        const bf16* row = vc + (size_t)t*NVC;

        // softmax over 25 logits
        float lg[4];
        #pragma unroll
        for (int k = 0; k < 4; k++) {
            int p = j + 8*k;
            lg[k] = (p < PP) ? b2f(row[656 + h*25 + p]) : -1e30f;
        }
        float m = fmaxf(fmaxf(lg[0], lg[1]), fmaxf(lg[2], lg[3]));
        m = fmaxf(m, __shfl_xor(m, 1));
        m = fmaxf(m, __shfl_xor(m, 2));
        m = fmaxf(m, __shfl_xor(m, 4));
        float aa[4], s = 0.f;
        #pragma unroll
        for (int k = 0; k < 4; k++) {
            aa[k] = (j + 8*k < PP) ? expf(lg[k] - m) : 0.f;
            s += aa[k];
        }
        s += __shfl_xor(s, 1);
        s += __shfl_xor(s, 2);
        s += __shfl_xor(s, 4);
        const float inv = 1.f / s;
        #pragma unroll
        for (int k = 0; k < 4; k++) aa[k] *= inv;

        // point coords
        const float rx96 = refp[(size_t)t*2 + 0]*96.f - 0.5f;
        const float ry96 = refp[(size_t)t*2 + 1]*96.f - 0.5f;
        const unsigned* offp = (const unsigned*)(row + 256 + h*50);
        float gxs[4], gys[4];
        int mnx = 95, mxx = 0, mny = 95, mxy = 0;
        #pragma unroll
        for (int k = 0; k < 4; k++) {
            const int p = j + 8*k;
            if (p >= PP) break;
            const unsigned uo = offp[p];
            gxs[k] = rx96 + lo_bf(uo);
            gys[k] = ry96 + hi_bf(uo);
            const int ix = (int)floorf(gxs[k]);
            const int iy = (int)floorf(gys[k]);
            mnx = min(mnx, min(max(ix,   0), WW-1));
            mxx = max(mxx, min(max(ix+1, 0), WW-1));
            mny = min(mny, min(max(iy,   0), HH-1));
            mxy = max(mxy, min(max(iy+1, 0), HH-1));
        }
        mnx = min(mnx, __shfl_xor(mnx, 1)); mxx = max(mxx, __shfl_xor(mxx, 1));
        mnx = min(mnx, __shfl_xor(mnx, 2)); mxx = max(mxx, __shfl_xor(mxx, 2));
        mnx = min(mnx, __shfl_xor(mnx, 4)); mxx = max(mxx, __shfl_xor(mxx, 4));
        mny = min(mny, __shfl_xor(mny, 1)); mxy = max(mxy, __shfl_xor(mxy, 1));
        mny = min(mny, __shfl_xor(mny, 2)); mxy = max(mxy, __shfl_xor(mxy, 2));
        mny = min(mny, __shfl_xor(mny, 4)); mxy = max(mxy, __shfl_xor(mxy, 4));
        const int bw = mxx - mnx + 1, bh = mxy - mny + 1;
        const int ok = (bw <= GW && bh <= GW) ? 1 : 0;
        if (j == 0)
            smeta[pair] = mnx | (mny << 7) | (bw << 14) | (bh << 21) | (ok << 28);

        __syncthreads();   // sgrid zeroing complete

        if (ok) {
            float* gp = sgrid + pair*36;
            #pragma unroll
            for (int k = 0; k < 4; k++) {
                const int p = j + 8*k;
                if (p >= PP) break;
                const float a = aa[k];
                const float x0f = floorf(gxs[k]), y0f = floorf(gys[k]);
                const float fx = gxs[k] - x0f, fy = gys[k] - y0f;
                const int ix = (int)x0f, iy = (int)y0f;
                #pragma unroll
                for (int d = 0; d < 4; d++) {
                    const int dx = d & 1, dy = d >> 1;
                    const int xi = ix + dx, yi = iy + dy;
                    const bool valid = (xi >= 0) & (xi <= WW-1) & (yi >= 0) & (yi <= HH-1);
                    const int xc = min(max(xi, 0), WW-1);
                    const int yc = min(max(yi, 0), HH-1);
                    const float wt = valid ? a * (dx ? fx : 1.f-fx) * (dy ? fy : 1.f-fy) : 0.f;
                    atomicAdd(&gp[(yc - mny)*GW + (xc - mnx)], wt);
                }
            }
        } else {
            #pragma unroll
            for (int k = 0; k < 4; k++) {
                const int p = j + 8*k;
                if (p >= PP) break;
                const float a = aa[k];
                const float x0f = floorf(gxs[k]), y0f = floorf(gys[k]);
                const float fx = gxs[k] - x0f, fy = gys[k] - y0f;
                const int ix = (int)x0f, iy = (int)y0f;
                Tap tp;
                #pragma unroll
                for (int d = 0; d < 4; d++) {
                    const int dx = d & 1, dy = d >> 1;
                    const int xi = ix + dx, yi = iy + dy;
                    const bool valid = (xi >= 0) & (xi <= WW-1) & (yi >= 0) & (yi <= HH-1);
                    const int xc = min(max(xi, 0), WW-1);
                    const int yc = min(max(yi, 0), HH-1);
                    tp.i[d] = (unsigned short)(yc*WW + xc);
                    tp.w[d] = (_Float16)(valid ? a * (dx ? fx : 1.f-fx) * (dy ? fy : 1.f-fy) : 0.f);
                }
                taps[tl*200 + h*25 + p] = tp;
            }
        }
    }
    __syncthreads();

    // ---- phase 2: one token per wave; lane = (head, 4-ch group)
    const int tok = tid >> 6, l = tid & 63;
    const int h   = l >> 3;
    const int g4  = l & 7;
    const int c0  = h*DHH + g4*4;
    const int t   = tbase + tok;
    const int n   = (t >= LQ) ? 1 : 0;
    const bf16* pv = val_d + (size_t)n*LQ*CC + c0;
    const int pair = tok*8 + h;

    const int meta = smeta[pair];
    const int ox = meta & 127, oy = (meta >> 7) & 127;
    const int bw = (meta >> 14) & 127, bh = (meta >> 21) & 127;
    const int ok = (meta >> 28) & 1;

    float a0 = 0.f, a1 = 0.f, a2 = 0.f, a3 = 0.f;
    if (ok) {
        const float* gp = sgrid + pair*36;
        for (int cy = 0; cy < bh; cy++) {
            const int rowpix = (oy + cy)*WW + ox;
            for (int cx = 0; cx < bw; cx++) {
                const float wt = gp[cy*GW + cx];
                if (wt != 0.f) {
                    const uint2 vv = *(const uint2*)(pv + (size_t)(rowpix + cx)*CC);
                    a0 += wt*lo_bf(vv.x); a1 += wt*hi_bf(vv.x);
                    a2 += wt*lo_bf(vv.y); a3 += wt*hi_bf(vv.y);
                }
            }
        }
    } else {
        const int pib = tok*200 + h*25;
        for (int p = 0; p < PP; p++) {
            const uint4 tv = *((const uint4*)taps + (pib + p));
            const _Float16* wp_ = (const _Float16*)&tv;
            const unsigned short* ip_ = (const unsigned short*)&tv + 4;
            #pragma unroll
            for (int d = 0; d < 4; d++) {
                const float wt = (float)wp_[d];
                const uint2 vv = *(const uint2*)(pv + (size_t)ip_[d]*CC);
                a0 += wt*lo_bf(vv.x); a1 += wt*hi_bf(vv.x);
                a2 += wt*lo_bf(vv.y); a3 += wt*hi_bf(vv.y);
            }
        }
    }
    bf16 o[4] = { f2b(a0), f2b(a1), f2b(a2), f2b(a3) };
    *(uint2*)(samp + (size_t)t*CC + c0) = *(uint2*)o;
}

// ---------------- Launch ---------------------------------------------------------
extern "C" void kernel_launch(void* const* d_in, const int* in_sizes, int n_in,
                              void* d_out, int out_size, void* d_ws, size_t ws_size,
                              hipStream_t stream)
{
    const float* x      = (const float*)d_in[0];
    const float* refp   = (const float*)d_in[1];
    const float* ln1_g  = (const float*)d_in[4];
    const float* ln1_b  = (const float*)d_in[5];
    const float* w_off  = (const float*)d_in[6];
    const float* b_off  = (const float*)d_in[7];
    const float* w_attn = (const float*)d_in[8];
    const float* b_attn = (const float*)d_in[9];
    const float* w_val  = (const float*)d_in[10];
    const float* b_val  = (const float*)d_in[11];
    const float* w_out  = (const float*)d_in[12];
    const float* b_out  = (const float*)d_in[13];
    const float* ln2_g  = (const float*)d_in[14];
    const float* ln2_b  = (const float*)d_in[15];
    const float* w_fc1  = (const float*)d_in[16];
    const float* b_fc1  = (const float*)d_in[17];
    const float* w_fc2  = (const float*)d_in[18];
    const float* b_fc2  = (const float*)d_in[19];

    // workspace layout
    char* wsb = (char*)d_ws;
    bf16*  q     = (bf16*)(wsb + 0);           //  9,437,184
    bf16*  vc    = (bf16*)(wsb + 9437184);     // 33,030,144 (TT*896 bf16)
    bf16*  samp  = (bf16*)(wsb + 42467328);    //  9,437,184
    float* x1    = (float*)(wsb + 51904512);   // 18,874,368
    bf16*  wvcT  = (bf16*)(wsb + 70778880);    //    458,752
    bf16*  wfc1T = (bf16*)(wsb + 71237632);    //    524,288
    bf16*  wfc2T = (bf16*)(wsb + 71761920);    //    524,288
    bf16*  woutT = (bf16*)(wsb + 72286208);    //    131,072
    float* bvc   = (float*)(wsb + 72417280);   //      3,584
    bf16*  val_d = (bf16*)(wsb + 72420864);    //  9,437,184 -> 81,858,048 total
    bf16*  hid   = (bf16*)(wsb + 0);           // overlays q+vc (42.5MB >= 37.7MB)
    bf16*  y0    = samp;                       // overlays samp after out-proj

    if (ws_size < 81858048) return;

    const dim3 blk(256);
    // 0. weight prep
    prep_all<<<dim3(3200), blk, 0, stream>>>(w_val, w_off, w_attn, w_fc1, w_fc2, w_out,
                                             b_val, b_off, b_attn,
                                             wvcT, wfc1T, wfc2T, woutT, bvc);
    // 1. LN1
    ln_kernel<<<dim3(TT/4), blk, 0, stream>>>(x, ln1_g, ln1_b, q);
    // 2. fused value|off|attn GEMM -> val_d (dense bf16) + vc (off/attn bf16)
    mfma_gemm<4,256,NVC,128><<<dim3(TT/128, NVC/128), blk, 0, stream>>>(q, wvcT, bvc, (void*)vc, nullptr, val_d);
    // 3. deformable sampling (softmax fused, tap dedup)
    sample_kernel<<<dim3(TT/TB), blk, 0, stream>>>(vc, val_d, refp, samp);
    // 4. out-projection + residual -> x1 (fp32); TM=64 for 576 blocks
    mfma_gemm<3,256,CC,64><<<dim3(TT/64, CC/128), blk, 0, stream>>>(samp, woutT, b_out, (void*)x1, x, nullptr);
    // 5. LN2
    ln_kernel<<<dim3(TT/4), blk, 0, stream>>>(x1, ln2_g, ln2_b, y0);
    // 6. fc1 + gelu
    mfma_gemm<2,256,HIDN,128><<<dim3(TT/128, HIDN/128), blk, 0, stream>>>(y0, wfc1T, b_fc1, (void*)hid, nullptr, nullptr);
    // 7. fc2 + residual -> out (fp32); TM=64
    mfma_gemm<3,HIDN,CC,64><<<dim3(TT/64, CC/128), blk, 0, stream>>>(hid, wfc2T, b_fc2, d_out, x1, nullptr);
}

// Round 11
// 243.545 us; speedup vs baseline: 1.2468x; 1.2468x over previous
//
#include <hip/hip_runtime.h>
#include <hip/hip_bf16.h>
#include <math.h>

typedef __hip_bfloat16 bf16;
typedef __attribute__((ext_vector_type(8))) short short8;
typedef __attribute__((ext_vector_type(4))) float f32x4;

#define NB 2
#define HH 96
#define WW 96
#define CC 256
#define NHEADS 8
#define PP 25
#define DHH 32
#define HIDN 1024
#define LQ (HH*WW)          // 9216
#define TT (NB*LQ)          // 18432
#define NVC 896             // 256 val + 400 off + 200 attn + 40 pad
#define TB 4                // tokens per sample block (128 threads)

__device__ __forceinline__ float b2f(bf16 v){ return __bfloat162float(v); }
__device__ __forceinline__ bf16  f2b(float v){ return __float2bfloat16(v); }
__device__ __forceinline__ float lo_bf(unsigned u){ return __uint_as_float(u << 16); }
__device__ __forceinline__ float hi_bf(unsigned u){ return __uint_as_float(u & 0xffff0000u); }

__device__ __forceinline__ void gl2lds16(const void* g, void* l) {
    __builtin_amdgcn_global_load_lds(
        (const __attribute__((address_space(1))) unsigned int*)g,
        (__attribute__((address_space(3))) unsigned int*)l, 16, 0, 0);
}

// ---------------- fused: LN1 (blocks 0..4607) + weight prep (blocks 4608..7807) --
__global__ __launch_bounds__(256) void fused_pre(const float* __restrict__ x,
                                                 const float* __restrict__ ln1_g,
                                                 const float* __restrict__ ln1_b,
                                                 bf16* __restrict__ q,
                                                 const float* __restrict__ w_val,
                                                 const float* __restrict__ w_off,
                                                 const float* __restrict__ w_attn,
                                                 const float* __restrict__ w_fc1,
                                                 const float* __restrict__ w_fc2,
                                                 const float* __restrict__ w_out,
                                                 const float* __restrict__ b_val,
                                                 const float* __restrict__ b_off,
                                                 const float* __restrict__ b_attn,
                                                 bf16* __restrict__ wvcT,
                                                 bf16* __restrict__ wfc1T,
                                                 bf16* __restrict__ wfc2T,
                                                 bf16* __restrict__ woutT,
                                                 float* __restrict__ bvc)
{
    const int bid = blockIdx.x;
    if (bid < 4608) {
        // ---- LN1: one wave per token
        const int t = bid*4 + (threadIdx.x >> 6);
        const int l = threadIdx.x & 63;
        const float4 v = *(const float4*)(x + (size_t)t*CC + l*4);
        float s  = v.x + v.y + v.z + v.w;
        float s2 = v.x*v.x + v.y*v.y + v.z*v.z + v.w*v.w;
        #pragma unroll
        for (int m = 1; m < 64; m <<= 1) { s += __shfl_xor(s, m); s2 += __shfl_xor(s2, m); }
        const float mean = s * (1.f/CC);
        const float var  = s2 * (1.f/CC) - mean*mean;
        const float rs   = 1.f / sqrtf(var + 1e-5f);
        const float4 gg = *(const float4*)(ln1_g + l*4);
        const float4 bb = *(const float4*)(ln1_b + l*4);
        bf16 o[4];
        o[0] = f2b((v.x-mean)*rs*gg.x + bb.x);
        o[1] = f2b((v.y-mean)*rs*gg.y + bb.y);
        o[2] = f2b((v.z-mean)*rs*gg.z + bb.z);
        o[3] = f2b((v.w-mean)*rs*gg.w + bb.w);
        *(uint2*)(q + (size_t)t*CC + l*4) = *(uint2*)o;
    } else {
        // ---- weight prep
        const int idx = (bid - 4608)*256 + threadIdx.x;   // < 819200
        if (idx < 229376) {                              // wvcT [896][256]
            int n = idx >> 8, k = idx & 255;
            float v = (n < 256) ? w_val[(size_t)k*256 + n]
                    : (n < 656) ? w_off[(size_t)k*400 + (n-256)]
                    : (n < 856) ? w_attn[(size_t)k*200 + (n-656)] : 0.f;
            wvcT[idx] = f2b(v);
        } else if (idx < 491520) {                       // wfc1T [1024][256]
            int j = idx - 229376; int n = j >> 8, k = j & 255;
            wfc1T[j] = f2b(w_fc1[(size_t)k*1024 + n]);
        } else if (idx < 753664) {                       // wfc2T [256][1024]
            int j = idx - 491520; int n = j >> 10, k = j & 1023;
            wfc2T[j] = f2b(w_fc2[(size_t)k*256 + n]);
        } else if (idx < 819200) {                       // woutT [256][256]
            int j = idx - 753664; int n = j >> 8, k = j & 255;
            woutT[j] = f2b(w_out[(size_t)k*256 + n]);
        }
        if (idx < NVC)
            bvc[idx] = (idx < 256) ? b_val[idx]
                     : (idx < 656) ? b_off[idx-256]
                     : (idx < 856) ? b_attn[idx-656] : 0.f;
    }
}

// ---------------- LayerNorm: one wave per token, 4 ch/lane ----------------------
__global__ __launch_bounds__(256) void ln_kernel(const float* __restrict__ x,
                                                 const float* __restrict__ g,
                                                 const float* __restrict__ b,
                                                 bf16* __restrict__ out)
{
    const int t = blockIdx.x*4 + (threadIdx.x >> 6);
    const int l = threadIdx.x & 63;
    const float4 v = *(const float4*)(x + (size_t)t*CC + l*4);
    float s  = v.x + v.y + v.z + v.w;
    float s2 = v.x*v.x + v.y*v.y + v.z*v.z + v.w*v.w;
    #pragma unroll
    for (int m = 1; m < 64; m <<= 1) { s += __shfl_xor(s, m); s2 += __shfl_xor(s2, m); }
    const float mean = s * (1.f/CC);
    const float var  = s2 * (1.f/CC) - mean*mean;
    const float rs   = 1.f / sqrtf(var + 1e-5f);
    const float4 gg = *(const float4*)(g + l*4);
    const float4 bb = *(const float4*)(b + l*4);
    bf16 o[4];
    o[0] = f2b((v.x-mean)*rs*gg.x + bb.x);
    o[1] = f2b((v.y-mean)*rs*gg.y + bb.y);
    o[2] = f2b((v.z-mean)*rs*gg.z + bb.z);
    o[3] = f2b((v.w-mean)*rs*gg.w + bb.w);
    *(uint2*)(out + (size_t)t*CC + l*4) = *(uint2*)o;
}

// ---------------- MFMA GEMM: A[M,K]bf16 @ Bt[N,K]bf16 + bias fp32 --------------
// tile TMx128, BK=64, 4 waves; XOR-swizzled LDS chunks. Compile-time K,N,TM.
// EPI: 0 = bf16; 2 = gelu->bf16; 3 = +resid(fp32)->fp32;
//      4 = col<256 -> dense bf16 val_d[row][col] (row stride 256), else bf16 vc
template<int EPI, int K, int N, int TM>
__global__ __launch_bounds__(256) void mfma_gemm(const bf16* __restrict__ A,
                                                 const bf16* __restrict__ Bt,
                                                 const float* __restrict__ bias,
                                                 void* __restrict__ outv,
                                                 const float* __restrict__ resid,
                                                 bf16* __restrict__ val_d)
{
    constexpr int AR  = TM/8;        // A regions (8 rows each)
    constexpr int TR  = AR + 16;     // + B regions (128 rows)
    constexpr int RPW = TR/4;        // regions staged per wave
    constexpr int NJ  = (TM==128) ? 4 : 2;
    __shared__ short As[TM*64];
    __shared__ short Bs[128*64];
    const int tid = threadIdx.x;
    const int w = tid >> 6, l = tid & 63;
    const int bm = blockIdx.x, bn = blockIdx.y;

    const bf16* sbase[RPW];
    short*      lbase[RPW];
    {
        const int lrow = l >> 3;
        const int q    = (l & 7) ^ lrow;
        #pragma unroll
        for (int j = 0; j < RPW; j++) {
            int r = w*RPW + j;
            bool isA = r < AR;
            int rr = isA ? r : r - AR;
            int row = rr*8 + lrow;
            size_t grow = (size_t)(isA ? (bm*TM + row) : (bn*128 + row));
            sbase[j] = (isA ? A : Bt) + grow*K + q*8;
            lbase[j] = (isA ? As : Bs) + rr*512;
        }
    }

    const int mbase = (TM==128) ? 64*(w >> 1) : 0;
    const int nbase = (TM==128) ? 64*(w & 1)  : 32*w;

    int aoff[2][4], boff[2][NJ];
    #pragma unroll
    for (int s = 0; s < 2; s++) {
        const int q = s*4 + (l >> 4);
        #pragma unroll
        for (int i = 0; i < 4; i++) {
            int m = mbase + i*16 + (l & 15);
            aoff[s][i] = (m*8 + (q ^ (m & 7))) * 8;
        }
        #pragma unroll
        for (int j = 0; j < NJ; j++) {
            int n = nbase + j*16 + (l & 15);
            boff[s][j] = (n*8 + (q ^ (n & 7))) * 8;
        }
    }

    f32x4 acc[4][NJ];
    #pragma unroll
    for (int i = 0; i < 4; i++)
        #pragma unroll
        for (int j = 0; j < NJ; j++)
            acc[i][j] = (f32x4){0.f, 0.f, 0.f, 0.f};

    for (int k0 = 0; k0 < K; k0 += 64) {
        #pragma unroll
        for (int j = 0; j < RPW; j++)
            gl2lds16(sbase[j] + k0, lbase[j]);
        __syncthreads();
        #pragma unroll
        for (int s = 0; s < 2; s++) {
            short8 af[4], bfr[NJ];
            #pragma unroll
            for (int i = 0; i < 4; i++)  af[i]  = *(const short8*)(As + aoff[s][i]);
            #pragma unroll
            for (int j = 0; j < NJ; j++) bfr[j] = *(const short8*)(Bs + boff[s][j]);
            #pragma unroll
            for (int i = 0; i < 4; i++)
                #pragma unroll
                for (int j = 0; j < NJ; j++)
                    acc[i][j] = __builtin_amdgcn_mfma_f32_16x16x32_bf16(af[i], bfr[j], acc[i][j], 0, 0, 0);
        }
        __syncthreads();
    }

    const int row0 = bm*TM + mbase + (l >> 4)*4;
    const int col0 = bn*128 + nbase + (l & 15);
    #pragma unroll
    for (int i = 0; i < 4; i++) {
        #pragma unroll
        for (int j = 0; j < NJ; j++) {
            const int col = col0 + j*16;
            const float bs = bias[col];
            #pragma unroll
            for (int r = 0; r < 4; r++) {
                const int row = row0 + i*16 + r;
                float v = acc[i][j][r] + bs;
                size_t o = (size_t)row * N + col;
                if (EPI == 0) {
                    ((bf16*)outv)[o] = f2b(v);
                } else if (EPI == 2) {
                    ((bf16*)outv)[o] = f2b(0.5f * v * (1.f + erff(v * 0.70710678118654752f)));
                } else if (EPI == 3) {
                    ((float*)outv)[o] = v + resid[o];
                } else { // 4: val cols -> dense [row][256] buffer; rest -> vc
                    if (col < 256) val_d[(size_t)row*CC + col] = f2b(v);
                    else           ((bf16*)outv)[o] = f2b(v);
                }
            }
        }
    }
}

// ---------------- Deformable sampling, phase-split, fused softmax ---------------
// block = 4 tokens, 128 threads (2 waves). R8's proven lane mapping (4 lanes per
// (t,h), 16B gathers) at R9's grid density: 4608 blocks, 12.8KB LDS ->
// ~12 blocks/CU resident for latency hiding.
// Phase 1: 32 (t,h) pairs x 4 threads: quad-shuffle softmax + 16B Tap records.
// Phase 2: lane = (token, head, channel-oct): 16B gathers from dense 512B rows.
// Batch-aware XCD swizzle: XCDs 0-3 -> batch 0, XCDs 4-7 -> batch 1.
struct __align__(16) Tap { _Float16 w[4]; unsigned short i[4]; };

__global__ __launch_bounds__(128) void sample_kernel(const bf16* __restrict__ vc,
                                                     const bf16* __restrict__ val_d,
                                                     const float* __restrict__ refp,
                                                     bf16* __restrict__ samp)
{
    __shared__ Tap taps[TB*200];                     // 12.8 KB
    const int b = blockIdx.x;                        // 4608 blocks
    const int xcd = b & 7, sub = b >> 3;             // 576 subs per xcd
    const int tbase = (xcd >> 2)*LQ + ((xcd & 3)*576 + sub)*TB;
    const int tid = threadIdx.x;

    // ---- phase 1: 4 threads per (t,h) pair (32 pairs x 4 = 128)
    {
        const int pair = tid >> 2;
        const int j    = tid & 3;
        const int tl   = pair >> 3;
        const int h    = pair & 7;
        const int t    = tbase + tl;
        const bf16* row = vc + (size_t)t*NVC;

        float lg[7];
        #pragma unroll
        for (int k = 0; k < 7; k++) {
            int p = j + 4*k;
            lg[k] = (p < PP) ? b2f(row[656 + h*25 + p]) : -1e30f;
        }
        float m = lg[0];
        #pragma unroll
        for (int k = 1; k < 7; k++) m = fmaxf(m, lg[k]);
        m = fmaxf(m, __shfl_xor(m, 1));
        m = fmaxf(m, __shfl_xor(m, 2));
        float s = 0.f;
        float ex[7];
        #pragma unroll
        for (int k = 0; k < 7; k++) {
            ex[k] = (j + 4*k < PP) ? expf(lg[k] - m) : 0.f;
            s += ex[k];
        }
        s += __shfl_xor(s, 1);
        s += __shfl_xor(s, 2);
        const float inv = 1.f / s;

        const float rx96 = refp[(size_t)t*2 + 0]*96.f - 0.5f;
        const float ry96 = refp[(size_t)t*2 + 1]*96.f - 0.5f;
        const unsigned* offp = (const unsigned*)(row + 256 + h*50);

        #pragma unroll
        for (int k = 0; k < 7; k++) {
            const int p = j + 4*k;
            if (p >= PP) break;
            const float a = ex[k] * inv;
            const unsigned uo = offp[p];
            const float gx = rx96 + lo_bf(uo);
            const float gy = ry96 + hi_bf(uo);
            const float x0f = floorf(gx), y0f = floorf(gy);
            const float fx = gx - x0f, fy = gy - y0f;
            const int ix = (int)x0f, iy = (int)y0f;
            Tap tp;
            #pragma unroll
            for (int d = 0; d < 4; d++) {
                const int dx = d & 1, dy = d >> 1;
                const int xi = ix + dx, yi = iy + dy;
                const bool valid = (xi >= 0) & (xi <= WW-1) & (yi >= 0) & (yi <= HH-1);
                const int xc = min(max(xi, 0), WW-1);
                const int yc = min(max(yi, 0), HH-1);
                tp.i[d] = (unsigned short)(yc*WW + xc);
                tp.w[d] = (_Float16)(valid ? a * (dx ? fx : 1.f-fx) * (dy ? fy : 1.f-fy) : 0.f);
            }
            taps[tl*200 + h*25 + p] = tp;
        }
    }
    __syncthreads();

    // ---- phase 2: 16B gathers; 2 waves x 2 tokens each
    const int wv_ = tid >> 6, l = tid & 63;
    const int tl  = wv_*2 + (l >> 5);
    const int r   = l & 31;
    const int h   = r >> 2, oct = r & 3;
    const int c0  = h*DHH + oct*8;
    const int t   = tbase + tl;
    const int n   = (t >= LQ) ? 1 : 0;
    const bf16* pv = val_d + (size_t)n*LQ*CC + c0;
    const int pib = tl*200 + h*25;

    float acc[8] = {0.f,0.f,0.f,0.f,0.f,0.f,0.f,0.f};
    for (int p = 0; p < PP; p++) {
        const uint4 tv = *((const uint4*)taps + (pib + p));
        const _Float16* wp_ = (const _Float16*)&tv;
        const unsigned short* ip_ = (const unsigned short*)&tv + 4;
        #pragma unroll
        for (int d = 0; d < 4; d++) {
            const float wt = (float)wp_[d];
            const uint4 vv = *(const uint4*)(pv + (size_t)ip_[d]*CC);
            acc[0] += wt*lo_bf(vv.x); acc[1] += wt*hi_bf(vv.x);
            acc[2] += wt*lo_bf(vv.y); acc[3] += wt*hi_bf(vv.y);
            acc[4] += wt*lo_bf(vv.z); acc[5] += wt*hi_bf(vv.z);
            acc[6] += wt*lo_bf(vv.w); acc[7] += wt*hi_bf(vv.w);
        }
    }
    bf16 o[8];
    #pragma unroll
    for (int j2 = 0; j2 < 8; j2++) o[j2] = f2b(acc[j2]);
    *(uint4*)(samp + (size_t)t*CC + c0) = *(uint4*)o;
}

// ---------------- Launch ---------------------------------------------------------
extern "C" void kernel_launch(void* const* d_in, const int* in_sizes, int n_in,
                              void* d_out, int out_size, void* d_ws, size_t ws_size,
                              hipStream_t stream)
{
    const float* x      = (const float*)d_in[0];
    const float* refp   = (const float*)d_in[1];
    const float* ln1_g  = (const float*)d_in[4];
    const float* ln1_b  = (const float*)d_in[5];
    const float* w_off  = (const float*)d_in[6];
    const float* b_off  = (const float*)d_in[7];
    const float* w_attn = (const float*)d_in[8];
    const float* b_attn = (const float*)d_in[9];
    const float* w_val  = (const float*)d_in[10];
    const float* b_val  = (const float*)d_in[11];
    const float* w_out  = (const float*)d_in[12];
    const float* b_out  = (const float*)d_in[13];
    const float* ln2_g  = (const float*)d_in[14];
    const float* ln2_b  = (const float*)d_in[15];
    const float* w_fc1  = (const float*)d_in[16];
    const float* b_fc1  = (const float*)d_in[17];
    const float* w_fc2  = (const float*)d_in[18];
    const float* b_fc2  = (const float*)d_in[19];

    // workspace layout
    char* wsb = (char*)d_ws;
    bf16*  q     = (bf16*)(wsb + 0);           //  9,437,184
    bf16*  vc    = (bf16*)(wsb + 9437184);     // 33,030,144 (TT*896 bf16)
    bf16*  samp  = (bf16*)(wsb + 42467328);    //  9,437,184
    float* x1    = (float*)(wsb + 51904512);   // 18,874,368
    bf16*  wvcT  = (bf16*)(wsb + 70778880);    //    458,752
    bf16*  wfc1T = (bf16*)(wsb + 71237632);    //    524,288
    bf16*  wfc2T = (bf16*)(wsb + 71761920);    //    524,288
    bf16*  woutT = (bf16*)(wsb + 72286208);    //    131,072
    float* bvc   = (float*)(wsb + 72417280);   //      3,584
    bf16*  val_d = (bf16*)(wsb + 72420864);    //  9,437,184 -> 81,858,048 total
    bf16*  hid   = (bf16*)(wsb + 0);           // overlays q+vc (42.5MB >= 37.7MB)
    bf16*  y0    = samp;                       // overlays samp after out-proj

    if (ws_size < 81858048) return;

    const dim3 blk(256);
    // 0. fused LN1 + weight prep (one dispatch)
    fused_pre<<<dim3(7808), blk, 0, stream>>>(x, ln1_g, ln1_b, q,
                                              w_val, w_off, w_attn, w_fc1, w_fc2, w_out,
                                              b_val, b_off, b_attn,
                                              wvcT, wfc1T, wfc2T, woutT, bvc);
    // 1. fused value|off|attn GEMM -> val_d (dense bf16) + vc (off/attn bf16)
    mfma_gemm<4,256,NVC,128><<<dim3(TT/128, NVC/128), blk, 0, stream>>>(q, wvcT, bvc, (void*)vc, nullptr, val_d);
    // 2. deformable sampling (softmax fused)
    sample_kernel<<<dim3(TT/TB), dim3(128), 0, stream>>>(vc, val_d, refp, samp);
    // 3. out-projection + residual -> x1 (fp32); TM=64 for 576 blocks
    mfma_gemm<3,256,CC,64><<<dim3(TT/64, CC/128), blk, 0, stream>>>(samp, woutT, b_out, (void*)x1, x, nullptr);
    // 4. LN2
    ln_kernel<<<dim3(TT/4), blk, 0, stream>>>(x1, ln2_g, ln2_b, y0);
    // 5. fc1 + gelu
    mfma_gemm<2,256,HIDN,128><<<dim3(TT/128, HIDN/128), blk, 0, stream>>>(y0, wfc1T, b_fc1, (void*)hid, nullptr, nullptr);
    // 6. fc2 + residual -> out (fp32); TM=64
    mfma_gemm<3,HIDN,CC,64><<<dim3(TT/64, CC/128), blk, 0, stream>>>(hid, wfc2T, b_fc2, d_out, x1, nullptr);
}